// Round 12
// baseline (3264.902 us; speedup 1.0000x reference)
//
#include <hip/hip_runtime.h>
#include <hip/hip_bf16.h>

typedef __attribute__((ext_vector_type(8))) short short8;
typedef __attribute__((ext_vector_type(4))) short short4_;
typedef __attribute__((ext_vector_type(4))) float f32x4;
typedef __attribute__((ext_vector_type(2))) unsigned int uint2_;

#define MFMA16(a,b,c) __builtin_amdgcn_mfma_f32_16x16x32_bf16((a),(b),(c),0,0,0)

// LDS-only barrier: does NOT drain vmcnt -> streamed weight loads stay in
// flight. Cross-wave deps inside the step loop are LDS-only.
#define BAR() do {                                         \
  __builtin_amdgcn_sched_barrier(0);                       \
  asm volatile("s_waitcnt lgkmcnt(0)" ::: "memory");       \
  __builtin_amdgcn_s_barrier();                            \
  __builtin_amdgcn_sched_barrier(0);                       \
} while (0)

// ---- helpers ----------------------------------------------------------------
__device__ __forceinline__ short f2bf(float f){
  union { float f; unsigned u; } v; v.f = f;
  unsigned u = v.u;
  u = u + 0x7fffu + ((u >> 16) & 1u);   // RNE
  return (short)(u >> 16);
}

// packed f32x2 -> bf16x2 (RNE), lo -> bits[15:0]
__device__ __forceinline__ unsigned cvt_pk_bf16(float lo, float hi){
  unsigned r;
  asm("v_cvt_pk_bf16_f32 %0, %1, %2" : "=v"(r) : "v"(lo), "v"(hi));
  return r;
}

__device__ __forceinline__ float gelu_f(float x){
  float x2 = x * x;
  float t  = __builtin_fmaf(0.044715f, x2, 1.0f);
  float u  = 2.30211416f * x * t;
  float e  = __builtin_exp2f(u);
  float r  = __builtin_amdgcn_rcpf(e + 1.0f);
  return x * (1.0f - r);
}

// ---- prep: transpose + bf16-blocked weight layouts into ws ------------------
// blocked layout: element slot = ((ntile*NKS + ks)*64 + lane)*8 + j
//   holds W[k = ks*32 + (lane>>4)*8 + j][n = ntile*16 + (lane&15)]  (i.e. W^T)
__global__ void prep_kernel(
    const float* __restrict__ rW1, const float* __restrict__ rW2,
    const float* __restrict__ fW1, const float* __restrict__ fW2,
    const float* __restrict__ mW1,
    short* __restrict__ w1t_all, short* __restrict__ w2t_all,
    short* __restrict__ mw1t)
{
  int id = blockIdx.x * 256 + threadIdx.x;
  short8 v;
  if (id < 32768) {                       // W1a^T: 2 nets x 16 nt x 16 ks x 64
    int l = id & 63, ks = (id >> 6) & 15, nt = (id >> 10) & 15, net = id >> 14;
    const float* W = net ? fW1 : rW1;     // [513][256]
    int n  = nt * 16 + (l & 15);
    int k0 = ks * 32 + (l >> 4) * 8;
    #pragma unroll
    for (int j = 0; j < 8; ++j) v[j] = f2bf(W[(size_t)(k0 + j) * 256 + n]);
    *(short8*)(w1t_all + (size_t)id * 8) = v;
  } else if (id < 65536) {                // W2^T: 2 nets x 32 nt x 8 ks x 64
    int id2 = id - 32768;
    int l = id2 & 63, ks = (id2 >> 6) & 7, nt = (id2 >> 9) & 31, net = id2 >> 14;
    const float* W = net ? fW2 : rW2;     // [256][512]
    int n  = nt * 16 + (l & 15);
    int k0 = ks * 32 + (l >> 4) * 8;
    #pragma unroll
    for (int j = 0; j < 8; ++j) v[j] = f2bf(W[(size_t)(k0 + j) * 512 + n]);
    *(short8*)(w2t_all + (size_t)id2 * 8) = v;
  } else {                                // mlpW1^T: 64 nt x 32 ks x 64
    int id3 = id - 65536;
    int l = id3 & 63, ks = (id3 >> 6) & 31, nt = id3 >> 11;
    int n  = nt * 16 + (l & 15);
    int k0 = ks * 32 + (l >> 4) * 8;
    #pragma unroll
    for (int j = 0; j < 8; ++j) v[j] = f2bf(mW1[(size_t)(k0 + j) * 1024 + n]);
    *(short8*)(mw1t + (size_t)id3 * 8) = v;
  }
}

// ---- fused persistent ODE integrator ---------------------------------------
// 512 wgs x 256 thr (4 waves, 32 rows each); 2 blocks co-resident per CU ->
// two independent barrier domains overlap (anti-phase pipe filling).
// net = blk&1 (XCD-segregated: blk%8 = XCD, parity constant per XCD).
// Wave shape 4 n-tiles x 2 m-tiles: halves LDS B-read traffic vs r7's 2x4
// (B amortized over n-tiles), at the cost of 2x the per-CU weight stream.
// Per-thread state identical to r7 (row x col invariant): zacc[8][2]=64,
// hacc[4][2]=32 (AGPR); worst-phase arch <=~100 (empirical cap 112/128).
#define LDW1(nt, ks) (*(const short8*)(w1t + ((size_t)(((4 * wv + (nt)) * 16 + (ks)) * 64 + l) * 8)))
#define LDW2(nt, ks) (*(const short8*)(w2t + ((size_t)(((8 * wv + (nt)) * 8  + (ks)) * 64 + l) * 8)))

__global__ __launch_bounds__(256) __attribute__((amdgpu_waves_per_eu(2)))
void ode_kernel(
    const float* __restrict__ z0,
    const short* __restrict__ w1t_all,
    const short* __restrict__ w2t_all,
    const float* __restrict__ rW1, const float* __restrict__ rb1, const float* __restrict__ rb2,
    const float* __restrict__ fW1, const float* __restrict__ fb1, const float* __restrict__ fb2,
    short* __restrict__ proj_all)
{
  __shared__ __align__(16) short zs[16384];   // 32 KB: z tile [32][512]
  __shared__ __align__(16) short hs[8192];    // 16 KB: h tile [32][256]
  __shared__ __align__(16) float cst[1024];   //  4 KB: b1 | W1t-row | -dt*b2

  const int blk = blockIdx.x;
  const int net = blk & 1;
  const int m0  = (blk >> 1) * 32;
  const int tid = threadIdx.x;
  const int wv  = tid >> 6;       // wave 0..3
  const int l   = tid & 63;
  const int l4  = l & 15;
  const int g   = l >> 4;         // 0..3

  const short* w1t = w1t_all + net * 131072;
  const short* w2t = w2t_all + net * 131072;
  const float* b1p = net ? fb1 : rb1;
  const float* b2p = net ? fb2 : rb2;
  const float* w1r = (net ? fW1 : rW1) + 512 * 256;   // t-row of W1
  short* proj = proj_all + (size_t)net * (8192 * 512);

  // ---- constants into LDS (256 threads -> 4 entries each) ----
  cst[tid]       = b1p[tid];
  cst[256 + tid] = w1r[tid];
  cst[512 + tid] = -0.01f * b2p[tid];
  cst[768 + tid] = -0.01f * b2p[256 + tid];

  // ---- z accumulator: zacc[ntile 0..7][m-subtile 0..1] ----
  f32x4 zacc[8][2];
  #pragma unroll
  for (int nt = 0; nt < 8; ++nt)
    #pragma unroll
    for (int mt = 0; mt < 2; ++mt)
      zacc[nt][mt] = *(const f32x4*)(z0 + (size_t)(m0 + 16 * mt + l4) * 512
                                        + (128 * wv + 16 * nt + 4 * g));

  // rolling prefetch banks (named scalars, reload-in-place)
  short8 pA0, pA1, pA2, pA3;                 // GEMM1 A bank A (4 ntiles)
  short8 pB0, pB1, pB2, pB3;                 // GEMM1 A bank B
  short8 qa0, qa1, qa2, qa3, qa4, qa5, qa6, qa7;  // GEMM2 A bank 0 (8 ntiles)
  short8 qb0, qb1, qb2, qb3, qb4, qb5, qb6, qb7;  // GEMM2 A bank 1

// one GEMM1 k-slice: b shared by all 4 ntiles; POST = refill stmts
#define G1F(ks, f0, f1, f2, f3, ...) do {                                      \
    _Pragma("unroll")                                                          \
    for (int mt = 0; mt < 2; ++mt){                                            \
      int m  = 16 * mt + l4;                                                   \
      int kk = (ks) * 32 + 8 * g;                                              \
      short8 b = *(const short8*)((const char*)zs +                            \
                   (m * 1024 + ((kk * 2) ^ ((m & 7) << 4))));                  \
      hacc[0][mt] = MFMA16(f0, b, hacc[0][mt]);                                \
      hacc[1][mt] = MFMA16(f1, b, hacc[1][mt]);                                \
      hacc[2][mt] = MFMA16(f2, b, hacc[2][mt]);                                \
      hacc[3][mt] = MFMA16(f3, b, hacc[3][mt]);                                \
    }                                                                          \
    __VA_ARGS__;                                                               \
  } while (0)

// one GEMM2 k-slice (all 8 z-ntiles); POST = refill stmts
#define G2K(ks, f0, f1, f2, f3, f4, f5, f6, f7, ...) do {                      \
    _Pragma("unroll")                                                          \
    for (int mt = 0; mt < 2; ++mt){                                            \
      int m  = 16 * mt + l4;                                                   \
      int kk = (ks) * 32 + 8 * g;                                              \
      short8 b = *(const short8*)((const char*)hs +                            \
                   (m * 512 + ((kk * 2) ^ ((m & 7) << 4))));                   \
      zacc[0][mt] = MFMA16(f0, b, zacc[0][mt]);                                \
      zacc[1][mt] = MFMA16(f1, b, zacc[1][mt]);                                \
      zacc[2][mt] = MFMA16(f2, b, zacc[2][mt]);                                \
      zacc[3][mt] = MFMA16(f3, b, zacc[3][mt]);                                \
      zacc[4][mt] = MFMA16(f4, b, zacc[4][mt]);                                \
      zacc[5][mt] = MFMA16(f5, b, zacc[5][mt]);                                \
      zacc[6][mt] = MFMA16(f6, b, zacc[6][mt]);                                \
      zacc[7][mt] = MFMA16(f7, b, zacc[7][mt]);                                \
    }                                                                          \
    __VA_ARGS__;                                                               \
  } while (0)

// GELU + h-store for ntile NT from hacc[NT] (cvt_pk packed)
#define GELU_STORE(NT) do {                                                    \
    f32x4 b1q = *(const f32x4*)&cst[64 * wv + 16 * (NT) + 4 * g];              \
    f32x4 w1q = *(const f32x4*)&cst[256 + 64 * wv + 16 * (NT) + 4 * g];        \
    _Pragma("unroll")                                                          \
    for (int mt = 0; mt < 2; ++mt){                                            \
      int m = 16 * mt + l4;                                                    \
      float gv[4];                                                             \
      _Pragma("unroll")                                                        \
      for (int r = 0; r < 4; ++r){                                             \
        float x  = hacc[NT][mt][r] + __builtin_fmaf(tw, w1q[r], b1q[r]);       \
        float x2 = x * x;                                                      \
        float tt = __builtin_fmaf(0.044715f, x2, 1.0f);                        \
        float uu = 2.30211416f * x * tt;                                       \
        float ee = __builtin_exp2f(uu);                                        \
        float rr = __builtin_amdgcn_rcpf(ee + 1.0f);                           \
        float xs = -0.01f * x;                                                 \
        gv[r] = __builtin_fmaf(-xs, rr, xs);  /* xs*(1-rr) */                  \
      }                                                                        \
      uint2_ pk;                                                               \
      pk[0] = cvt_pk_bf16(gv[0], gv[1]);                                       \
      pk[1] = cvt_pk_bf16(gv[2], gv[3]);                                       \
      int nq = 64 * wv + 16 * (NT) + 4 * g;                                    \
      int byte = m * 512 + ((nq * 2) ^ ((m & 7) << 4));                        \
      *(uint2_*)((char*)hs + byte) = pk;                                       \
    }                                                                          \
  } while (0)

  for (int i = 0; i < 100; ++i){
    float tw = 1.0f - 0.01f * (float)i;

    // prefetch GEMM1 ks 0,1 for all 4 ntiles (fly during z-store + barrier)
    pA0 = LDW1(0, 0); pA1 = LDW1(1, 0); pA2 = LDW1(2, 0); pA3 = LDW1(3, 0);
    pB0 = LDW1(0, 1); pB1 = LDW1(1, 1); pB2 = LDW1(2, 1); pB3 = LDW1(3, 1);

    // ---- store z (bf16) into LDS, swizzled (cvt_pk packed) ----
    #pragma unroll
    for (int nt = 0; nt < 8; ++nt)
      #pragma unroll
      for (int mt = 0; mt < 2; ++mt){
        int m  = 16 * mt + l4;
        int kq = 128 * wv + 16 * nt + 4 * g;
        uint2_ pk;
        pk[0] = cvt_pk_bf16(zacc[nt][mt][0], zacc[nt][mt][1]);
        pk[1] = cvt_pk_bf16(zacc[nt][mt][2], zacc[nt][mt][3]);
        int byte = m * 1024 + ((kq * 2) ^ ((m & 7) << 4));
        *(uint2_*)((char*)zs + byte) = pk;
      }
    BAR();

    // ---- GEMM1: hT[n][m] = W1a^T * z^T, K=512, two rolling 4-wide banks ----
    f32x4 hacc[4][2];
    #pragma unroll
    for (int nt = 0; nt < 4; ++nt)
      #pragma unroll
      for (int mt = 0; mt < 2; ++mt) hacc[nt][mt] = (f32x4){0.f,0.f,0.f,0.f};

    G1F( 0, pA0,pA1,pA2,pA3, pA0=LDW1(0, 2); pA1=LDW1(1, 2); pA2=LDW1(2, 2); pA3=LDW1(3, 2));
    G1F( 1, pB0,pB1,pB2,pB3, pB0=LDW1(0, 3); pB1=LDW1(1, 3); pB2=LDW1(2, 3); pB3=LDW1(3, 3));
    G1F( 2, pA0,pA1,pA2,pA3, pA0=LDW1(0, 4); pA1=LDW1(1, 4); pA2=LDW1(2, 4); pA3=LDW1(3, 4));
    G1F( 3, pB0,pB1,pB2,pB3, pB0=LDW1(0, 5); pB1=LDW1(1, 5); pB2=LDW1(2, 5); pB3=LDW1(3, 5));
    G1F( 4, pA0,pA1,pA2,pA3, pA0=LDW1(0, 6); pA1=LDW1(1, 6); pA2=LDW1(2, 6); pA3=LDW1(3, 6));
    G1F( 5, pB0,pB1,pB2,pB3, pB0=LDW1(0, 7); pB1=LDW1(1, 7); pB2=LDW1(2, 7); pB3=LDW1(3, 7));
    G1F( 6, pA0,pA1,pA2,pA3, pA0=LDW1(0, 8); pA1=LDW1(1, 8); pA2=LDW1(2, 8); pA3=LDW1(3, 8));
    G1F( 7, pB0,pB1,pB2,pB3, pB0=LDW1(0, 9); pB1=LDW1(1, 9); pB2=LDW1(2, 9); pB3=LDW1(3, 9));
    G1F( 8, pA0,pA1,pA2,pA3, pA0=LDW1(0,10); pA1=LDW1(1,10); pA2=LDW1(2,10); pA3=LDW1(3,10));
    G1F( 9, pB0,pB1,pB2,pB3, pB0=LDW1(0,11); pB1=LDW1(1,11); pB2=LDW1(2,11); pB3=LDW1(3,11));
    G1F(10, pA0,pA1,pA2,pA3, pA0=LDW1(0,12); pA1=LDW1(1,12); pA2=LDW1(2,12); pA3=LDW1(3,12));
    G1F(11, pB0,pB1,pB2,pB3, pB0=LDW1(0,13); pB1=LDW1(1,13); pB2=LDW1(2,13); pB3=LDW1(3,13));
    G1F(12, pA0,pA1,pA2,pA3, pA0=LDW1(0,14); pA1=LDW1(1,14); pA2=LDW1(2,14); pA3=LDW1(3,14));
    G1F(13, pB0,pB1,pB2,pB3, pB0=LDW1(0,15); pB1=LDW1(1,15); pB2=LDW1(2,15); pB3=LDW1(3,15));
    // tails: bank A dead after slice 14 -> start GEMM2 bank 0
    G1F(14, pA0,pA1,pA2,pA3,
        qa0=LDW2(0,0); qa1=LDW2(1,0); qa2=LDW2(2,0); qa3=LDW2(3,0);
        qa4=LDW2(4,0); qa5=LDW2(5,0); qa6=LDW2(6,0); qa7=LDW2(7,0));
    G1F(15, pB0,pB1,pB2,pB3, );
    // p-banks now dead.

    // ---- GELU, scale by -dt, write h (bf16) into hs ----
    GELU_STORE(0);
    GELU_STORE(1);

    // q bank1: flies under GELU 2,3 + h-store drain + barrier
    qb0=LDW2(0,1); qb1=LDW2(1,1); qb2=LDW2(2,1); qb3=LDW2(3,1);
    qb4=LDW2(4,1); qb5=LDW2(5,1); qb6=LDW2(6,1); qb7=LDW2(7,1);

    GELU_STORE(2);
    GELU_STORE(3);
    BAR();

    // ---- GEMM2: z += W2^T * h^T  (K=256), two rolling 8-wide banks ----
    G2K(0, qa0,qa1,qa2,qa3,qa4,qa5,qa6,qa7,
        qa0=LDW2(0,2); qa1=LDW2(1,2); qa2=LDW2(2,2); qa3=LDW2(3,2);
        qa4=LDW2(4,2); qa5=LDW2(5,2); qa6=LDW2(6,2); qa7=LDW2(7,2));
    G2K(1, qb0,qb1,qb2,qb3,qb4,qb5,qb6,qb7,
        qb0=LDW2(0,3); qb1=LDW2(1,3); qb2=LDW2(2,3); qb3=LDW2(3,3);
        qb4=LDW2(4,3); qb5=LDW2(5,3); qb6=LDW2(6,3); qb7=LDW2(7,3));
    G2K(2, qa0,qa1,qa2,qa3,qa4,qa5,qa6,qa7,
        qa0=LDW2(0,4); qa1=LDW2(1,4); qa2=LDW2(2,4); qa3=LDW2(3,4);
        qa4=LDW2(4,4); qa5=LDW2(5,4); qa6=LDW2(6,4); qa7=LDW2(7,4));
    G2K(3, qb0,qb1,qb2,qb3,qb4,qb5,qb6,qb7,
        qb0=LDW2(0,5); qb1=LDW2(1,5); qb2=LDW2(2,5); qb3=LDW2(3,5);
        qb4=LDW2(4,5); qb5=LDW2(5,5); qb6=LDW2(6,5); qb7=LDW2(7,5));
    G2K(4, qa0,qa1,qa2,qa3,qa4,qa5,qa6,qa7,
        qa0=LDW2(0,6); qa1=LDW2(1,6); qa2=LDW2(2,6); qa3=LDW2(3,6);
        qa4=LDW2(4,6); qa5=LDW2(5,6); qa6=LDW2(6,6); qa7=LDW2(7,6));
    G2K(5, qb0,qb1,qb2,qb3,qb4,qb5,qb6,qb7,
        qb0=LDW2(0,7); qb1=LDW2(1,7); qb2=LDW2(2,7); qb3=LDW2(3,7);
        qb4=LDW2(4,7); qb5=LDW2(5,7); qb6=LDW2(6,7); qb7=LDW2(7,7));
    G2K(6, qa0,qa1,qa2,qa3,qa4,qa5,qa6,qa7, );
    G2K(7, qb0,qb1,qb2,qb3,qb4,qb5,qb6,qb7, );

    // ---- -dt*b2 bias ----
    #pragma unroll
    for (int nt = 0; nt < 8; ++nt){
      f32x4 b2q = *(const f32x4*)&cst[512 + 128 * wv + 16 * nt + 4 * g];
      #pragma unroll
      for (int mt = 0; mt < 2; ++mt)
        #pragma unroll
        for (int r = 0; r < 4; ++r)
          zacc[nt][mt][r] += b2q[r];
    }
  }
#undef G1F
#undef G2K
#undef GELU_STORE

  // ---- write projection (bf16) ----
  #pragma unroll
  for (int nt = 0; nt < 8; ++nt)
    #pragma unroll
    for (int mt = 0; mt < 2; ++mt){
      int mg = m0 + 16 * mt + l4;
      int nq = 128 * wv + 16 * nt + 4 * g;
      uint2_ pk;
      pk[0] = cvt_pk_bf16(zacc[nt][mt][0], zacc[nt][mt][1]);
      pk[1] = cvt_pk_bf16(zacc[nt][mt][2], zacc[nt][mt][3]);
      *(uint2_*)(proj + (size_t)mg * 512 + nq) = pk;
    }
}

// ---- classifier: logits = gelu([real||fake] @ W1 + b1) @ W2 + b2 -----------
__global__ __launch_bounds__(512, 2) void cls_kernel(
    const short* __restrict__ mw1t,
    const short* __restrict__ proj_all,
    const float* __restrict__ mb1,
    const float* __restrict__ mw2,
    const float* __restrict__ mb2,
    float* __restrict__ out)
{
  __shared__ __align__(16) float sb1[1024];
  __shared__ __align__(16) float sw2[2048];
  __shared__ __align__(16) float sred[2048];

  const int blk = blockIdx.x;
  const int m0  = blk * 32;
  const int tid = threadIdx.x;
  const int w = tid >> 6, l = tid & 63, l4 = l & 15, g = l >> 4;

  #pragma unroll
  for (int j = 0; j < 2; ++j) sb1[tid + 512 * j] = mb1[tid + 512 * j];
  #pragma unroll
  for (int j = 0; j < 4; ++j) sw2[tid + 512 * j] = mw2[tid + 512 * j];
  __syncthreads();

  float lacc[2][2] = {{0.f, 0.f}, {0.f, 0.f}};

  for (int rnd = 0; rnd < 4; ++rnd){
    f32x4 hacc[2][2];
    #pragma unroll
    for (int nt = 0; nt < 2; ++nt)
      #pragma unroll
      for (int mt = 0; mt < 2; ++mt)
        hacc[nt][mt] = (f32x4){0.f, 0.f, 0.f, 0.f};

    #pragma unroll
    for (int ks = 0; ks < 32; ++ks){
      int gnt0 = rnd * 16 + 2 * w;
      short8 a0 = *(const short8*)(mw1t + ((size_t)((gnt0    ) * 32 + ks) * 64 + l) * 8);
      short8 a1 = *(const short8*)(mw1t + ((size_t)((gnt0 + 1) * 32 + ks) * 64 + l) * 8);
      int k = ks * 32 + 8 * g;   // combined-dim index; uniform side per ks
      const short* src = (k < 512) ? (proj_all + k)
                                   : (proj_all + ((size_t)8192 * 512 - 512) + k);
      #pragma unroll
      for (int mt = 0; mt < 2; ++mt){
        int mg = m0 + 16 * mt + l4;
        short8 b = *(const short8*)(src + (size_t)mg * 512);
        hacc[0][mt] = MFMA16(a0, b, hacc[0][mt]);
        hacc[1][mt] = MFMA16(a1, b, hacc[1][mt]);
      }
    }
    #pragma unroll
    for (int nt = 0; nt < 2; ++nt){
      int nq = (rnd * 16 + 2 * w + nt) * 16 + 4 * g;
      f32x4 bb = *(const f32x4*)(sb1 + nq);
      #pragma unroll
      for (int r = 0; r < 4; ++r){
        float w2c0 = sw2[(nq + r) * 2 + 0];
        float w2c1 = sw2[(nq + r) * 2 + 1];
        #pragma unroll
        for (int mt = 0; mt < 2; ++mt){
          float x  = hacc[nt][mt][r] + bb[r];
          float gv = gelu_f(x);
          lacc[mt][0] = __builtin_fmaf(gv, w2c0, lacc[mt][0]);
          lacc[mt][1] = __builtin_fmaf(gv, w2c1, lacc[mt][1]);
        }
      }
    }
  }

  int part = w * 4 + g;  // 0..31
  #pragma unroll
  for (int mt = 0; mt < 2; ++mt)
    #pragma unroll
    for (int c = 0; c < 2; ++c)
      sred[((16 * mt + l4) * 2 + c) * 32 + part] = lacc[mt][c];
  __syncthreads();
  if (tid < 64){
    int m = tid >> 1, c = tid & 1;
    float s = 0.f;
    #pragma unroll
    for (int p2 = 0; p2 < 32; ++p2) s += sred[(m * 2 + c) * 32 + p2];
    out[(size_t)(m0 + m) * 2 + c] = s + mb2[c];
  }
}

// ---- launch -----------------------------------------------------------------
extern "C" void kernel_launch(void* const* d_in, const int* in_sizes, int n_in,
                              void* d_out, int out_size, void* d_ws, size_t ws_size,
                              hipStream_t stream)
{
  const float* z0  = (const float*)d_in[0];
  const float* rW1 = (const float*)d_in[1];
  const float* rb1 = (const float*)d_in[2];
  const float* rW2 = (const float*)d_in[3];
  const float* rb2 = (const float*)d_in[4];
  const float* fW1 = (const float*)d_in[5];
  const float* fb1 = (const float*)d_in[6];
  const float* fW2 = (const float*)d_in[7];
  const float* fb2 = (const float*)d_in[8];
  const float* mW1 = (const float*)d_in[9];
  const float* mb1 = (const float*)d_in[10];
  const float* mW2 = (const float*)d_in[11];
  const float* mb2 = (const float*)d_in[12];
  float* out = (float*)d_out;

  char* ws = (char*)d_ws;
  short* w1t_all = (short*)(ws);                 //   524288 B (2 nets)
  short* w2t_all = (short*)(ws + 524288);        //   524288 B (2 nets)
  short* mw1t    = (short*)(ws + 1048576);       //  2097152 B
  short* proj    = (short*)(ws + 3145728);       // 16777216 B (real||fake, bf16)

  prep_kernel<<<768, 256, 0, stream>>>(rW1, rW2, fW1, fW2, mW1, w1t_all, w2t_all, mw1t);
  ode_kernel<<<512, 256, 0, stream>>>(z0, w1t_all, w2t_all,
                                      rW1, rb1, rb2, fW1, fb1, fb2, proj);
  cls_kernel<<<256, 512, 0, stream>>>(mw1t, proj, mb1, mW2, mb2, out);
}

// Round 13
// 1038.861 us; speedup vs baseline: 3.1428x; 3.1428x over previous
//
#include <hip/hip_runtime.h>
#include <hip/hip_bf16.h>

typedef __attribute__((ext_vector_type(8))) short short8;
typedef __attribute__((ext_vector_type(4))) short short4_;
typedef __attribute__((ext_vector_type(4))) float f32x4;
typedef __attribute__((ext_vector_type(2))) unsigned int uint2_;

#define MFMA16(a,b,c) __builtin_amdgcn_mfma_f32_16x16x32_bf16((a),(b),(c),0,0,0)

// LDS-only barrier: does NOT drain vmcnt -> streamed weight loads stay in
// flight. Cross-wave deps inside the step loop are LDS-only.
#define BAR() do {                                         \
  __builtin_amdgcn_sched_barrier(0);                       \
  asm volatile("s_waitcnt lgkmcnt(0)" ::: "memory");       \
  __builtin_amdgcn_s_barrier();                            \
  __builtin_amdgcn_sched_barrier(0);                       \
} while (0)

// ---- helpers ----------------------------------------------------------------
__device__ __forceinline__ short f2bf(float f){
  union { float f; unsigned u; } v; v.f = f;
  unsigned u = v.u;
  u = u + 0x7fffu + ((u >> 16) & 1u);   // RNE
  return (short)(u >> 16);
}

// packed f32x2 -> bf16x2 (RNE), lo -> bits[15:0]
__device__ __forceinline__ unsigned cvt_pk_bf16(float lo, float hi){
  unsigned r;
  asm("v_cvt_pk_bf16_f32 %0, %1, %2" : "=v"(r) : "v"(lo), "v"(hi));
  return r;
}

__device__ __forceinline__ float gelu_f(float x){
  float x2 = x * x;
  float t  = __builtin_fmaf(0.044715f, x2, 1.0f);
  float u  = 2.30211416f * x * t;
  float e  = __builtin_exp2f(u);
  float r  = __builtin_amdgcn_rcpf(e + 1.0f);
  return x * (1.0f - r);
}

// ---- prep: transpose + bf16-blocked weight layouts into ws ------------------
// blocked layout: element slot = ((ntile*NKS + ks)*64 + lane)*8 + j
//   holds W[k = ks*32 + (lane>>4)*8 + j][n = ntile*16 + (lane&15)]  (i.e. W^T)
__global__ void prep_kernel(
    const float* __restrict__ rW1, const float* __restrict__ rW2,
    const float* __restrict__ fW1, const float* __restrict__ fW2,
    const float* __restrict__ mW1,
    short* __restrict__ w1t_all, short* __restrict__ w2t_all,
    short* __restrict__ mw1t)
{
  int id = blockIdx.x * 256 + threadIdx.x;
  short8 v;
  if (id < 32768) {                       // W1a^T: 2 nets x 16 nt x 16 ks x 64
    int l = id & 63, ks = (id >> 6) & 15, nt = (id >> 10) & 15, net = id >> 14;
    const float* W = net ? fW1 : rW1;     // [513][256]
    int n  = nt * 16 + (l & 15);
    int k0 = ks * 32 + (l >> 4) * 8;
    #pragma unroll
    for (int j = 0; j < 8; ++j) v[j] = f2bf(W[(size_t)(k0 + j) * 256 + n]);
    *(short8*)(w1t_all + (size_t)id * 8) = v;
  } else if (id < 65536) {                // W2^T: 2 nets x 32 nt x 8 ks x 64
    int id2 = id - 32768;
    int l = id2 & 63, ks = (id2 >> 6) & 7, nt = (id2 >> 9) & 31, net = id2 >> 14;
    const float* W = net ? fW2 : rW2;     // [256][512]
    int n  = nt * 16 + (l & 15);
    int k0 = ks * 32 + (l >> 4) * 8;
    #pragma unroll
    for (int j = 0; j < 8; ++j) v[j] = f2bf(W[(size_t)(k0 + j) * 512 + n]);
    *(short8*)(w2t_all + (size_t)id2 * 8) = v;
  } else {                                // mlpW1^T: 64 nt x 32 ks x 64
    int id3 = id - 65536;
    int l = id3 & 63, ks = (id3 >> 6) & 31, nt = id3 >> 11;
    int n  = nt * 16 + (l & 15);
    int k0 = ks * 32 + (l >> 4) * 8;
    #pragma unroll
    for (int j = 0; j < 8; ++j) v[j] = f2bf(mW1[(size_t)(k0 + j) * 1024 + n]);
    *(short8*)(mw1t + (size_t)id3 * 8) = v;
  }
}

// ---- fused persistent ODE integrator ---------------------------------------
// 256 wgs; net = blk&1 (XCD-segregated under blk%8 round-robin), rows blk>>1.
// z in f32 MFMA accumulators across all 100 steps.
//
// FINAL (r7 optimum). SPILL-PROOF phase-disjoint arch-register plan:
//   GEMM1 phase: p-slots 32 (depth-2) + addr temps   (~75 total)
//   GELU  phase: q-banks 32-64 + GELU temps          (~80 total)
//   GEMM2 phase: q-banks 64 + addr temps             (~85 total)
// zacc(64) + hacc(32) are MFMA accumulators (AGPR side of unified file).
// Empirical rule (r5-r12): worst-phase arch demand must stay <= ~112; the
// 128-arch cap is hard. Every perturbation (depth-3/4 prefetch, 16-wave,
// 256-thr bank-split, weight reg/LDS caches) re-tripped scratch spills.
#define LDW1(nt, ks) (*(const short8*)(w1t + ((size_t)(((2 * w + (nt)) * 16 + (ks)) * 64 + l) * 8)))
#define LDW2(nt, ks) (*(const short8*)(w2t + ((size_t)(((4 * w + (nt)) * 8  + (ks)) * 64 + l) * 8)))

__global__ __launch_bounds__(512) __attribute__((amdgpu_waves_per_eu(2)))
void ode_kernel(
    const float* __restrict__ z0,
    const short* __restrict__ w1t_all,
    const short* __restrict__ w2t_all,
    const float* __restrict__ rW1, const float* __restrict__ rb1, const float* __restrict__ rb2,
    const float* __restrict__ fW1, const float* __restrict__ fb1, const float* __restrict__ fb2,
    short* __restrict__ proj_all)
{
  __shared__ __align__(16) short zs[32768];   // 64 KB: z tile [64][512]
  __shared__ __align__(16) short hs[16384];   // 32 KB: h tile [64][256]
  __shared__ __align__(16) float cst[1024];   //  4 KB: b1 | W1t-row | -dt*b2

  const int blk = blockIdx.x;
  const int net = blk & 1;
  const int m0  = (blk >> 1) * 64;
  const int tid = threadIdx.x;
  const int w   = tid >> 6;       // wave 0..7
  const int l   = tid & 63;
  const int l4  = l & 15;
  const int g   = l >> 4;         // 0..3

  const short* w1t = w1t_all + net * 131072;
  const short* w2t = w2t_all + net * 131072;
  const float* b1p = net ? fb1 : rb1;
  const float* b2p = net ? fb2 : rb2;
  const float* w1r = (net ? fW1 : rW1) + 512 * 256;   // t-row of W1
  short* proj = proj_all + (size_t)net * (8192 * 512);

  // ---- constants into LDS ----
  if (tid < 256)       cst[tid] = b1p[tid];
  else                 cst[tid] = w1r[tid - 256];
  cst[512 + tid] = -0.01f * b2p[tid];

  // ---- z accumulator ----
  f32x4 zacc[4][4];
  #pragma unroll
  for (int nt = 0; nt < 4; ++nt)
    #pragma unroll
    for (int mt = 0; mt < 4; ++mt)
      zacc[nt][mt] = *(const f32x4*)(z0 + (size_t)(m0 + 16 * mt + l4) * 512
                                        + (64 * w + 16 * nt + 4 * g));

  // rolling prefetch slots (named scalars, reload-in-place)
  short8 pA0, pB0, pA1, pB1;        // GEMM1 A (both ntiles), depth 2
  short8 q00, q01, q02, q03;        // GEMM2 A bank 0 (4 ntiles)
  short8 q10, q11, q12, q13;        // GEMM2 A bank 1

// one fused GEMM1 k-slice: b shared by BOTH ntiles; POST = refill stmts
#define G1F(ks, pa, pb, ...) do {                                              \
    _Pragma("unroll")                                                          \
    for (int mt = 0; mt < 4; ++mt){                                            \
      int m  = 16 * mt + l4;                                                   \
      int kk = (ks) * 32 + 8 * g;                                              \
      short8 b = *(const short8*)((const char*)zs +                            \
                   (m * 1024 + ((kk * 2) ^ ((m & 7) << 4))));                  \
      hacc[0][mt] = MFMA16(pa, b, hacc[0][mt]);                                \
      hacc[1][mt] = MFMA16(pb, b, hacc[1][mt]);                                \
    }                                                                          \
    __VA_ARGS__;                                                               \
  } while (0)

// one GEMM2 k-slice (all 4 z-ntiles); POST = refill stmts
#define G2K(ks, qa, qb, qc, qd, ...) do {                                      \
    _Pragma("unroll")                                                          \
    for (int mt = 0; mt < 4; ++mt){                                            \
      int m  = 16 * mt + l4;                                                   \
      int kk = (ks) * 32 + 8 * g;                                              \
      short8 b = *(const short8*)((const char*)hs +                            \
                   (m * 512 + ((kk * 2) ^ ((m & 7) << 4))));                   \
      zacc[0][mt] = MFMA16(qa, b, zacc[0][mt]);                                \
      zacc[1][mt] = MFMA16(qb, b, zacc[1][mt]);                                \
      zacc[2][mt] = MFMA16(qc, b, zacc[2][mt]);                                \
      zacc[3][mt] = MFMA16(qd, b, zacc[3][mt]);                                \
    }                                                                          \
    __VA_ARGS__;                                                               \
  } while (0)

// GELU + h-store for ntile NT from hacc[NT] (cvt_pk packed)
#define GELU_STORE(NT) do {                                                    \
    f32x4 b1q = *(const f32x4*)&cst[32 * w + 16 * (NT) + 4 * g];               \
    f32x4 w1q = *(const f32x4*)&cst[256 + 32 * w + 16 * (NT) + 4 * g];         \
    _Pragma("unroll")                                                          \
    for (int mt = 0; mt < 4; ++mt){                                            \
      int m = 16 * mt + l4;                                                    \
      float gv[4];                                                             \
      _Pragma("unroll")                                                        \
      for (int r = 0; r < 4; ++r){                                             \
        float x  = hacc[NT][mt][r] + __builtin_fmaf(tw, w1q[r], b1q[r]);       \
        float x2 = x * x;                                                      \
        float tt = __builtin_fmaf(0.044715f, x2, 1.0f);                        \
        float uu = 2.30211416f * x * tt;                                       \
        float ee = __builtin_exp2f(uu);                                        \
        float rr = __builtin_amdgcn_rcpf(ee + 1.0f);                           \
        float xs = -0.01f * x;                                                 \
        gv[r] = __builtin_fmaf(-xs, rr, xs);  /* xs*(1-rr) */                  \
      }                                                                        \
      uint2_ pk;                                                               \
      pk[0] = cvt_pk_bf16(gv[0], gv[1]);                                       \
      pk[1] = cvt_pk_bf16(gv[2], gv[3]);                                       \
      int nq = 32 * w + 16 * (NT) + 4 * g;                                     \
      int byte = m * 512 + ((nq * 2) ^ ((m & 7) << 4));                        \
      *(uint2_*)((char*)hs + byte) = pk;                                       \
    }                                                                          \
  } while (0)

  for (int i = 0; i < 100; ++i){
    float tw = 1.0f - 0.01f * (float)i;

    // prefetch GEMM1 ks 0,1 for both ntiles (flies during z-store + barrier)
    pA0 = LDW1(0, 0); pB0 = LDW1(1, 0);
    pA1 = LDW1(0, 1); pB1 = LDW1(1, 1);

    // ---- store z (bf16) into LDS, swizzled (cvt_pk packed) ----
    #pragma unroll
    for (int nt = 0; nt < 4; ++nt)
      #pragma unroll
      for (int mt = 0; mt < 4; ++mt){
        int m  = 16 * mt + l4;
        int kq = 64 * w + 16 * nt + 4 * g;
        uint2_ pk;
        pk[0] = cvt_pk_bf16(zacc[nt][mt][0], zacc[nt][mt][1]);
        pk[1] = cvt_pk_bf16(zacc[nt][mt][2], zacc[nt][mt][3]);
        int byte = m * 1024 + ((kq * 2) ^ ((m & 7) << 4));
        *(uint2_*)((char*)zs + byte) = pk;
      }
    BAR();

    // ---- GEMM1 (fused): hT[n][m] = W1a^T * z^T, K=512, b shared over 2 nt --
    f32x4 hacc[2][4];
    #pragma unroll
    for (int nt = 0; nt < 2; ++nt)
      #pragma unroll
      for (int mt = 0; mt < 4; ++mt) hacc[nt][mt] = (f32x4){0.f,0.f,0.f,0.f};

    G1F( 0, pA0, pB0, pA0 = LDW1(0, 2);  pB0 = LDW1(1, 2));
    G1F( 1, pA1, pB1, pA1 = LDW1(0, 3);  pB1 = LDW1(1, 3));
    G1F( 2, pA0, pB0, pA0 = LDW1(0, 4);  pB0 = LDW1(1, 4));
    G1F( 3, pA1, pB1, pA1 = LDW1(0, 5);  pB1 = LDW1(1, 5));
    G1F( 4, pA0, pB0, pA0 = LDW1(0, 6);  pB0 = LDW1(1, 6));
    G1F( 5, pA1, pB1, pA1 = LDW1(0, 7);  pB1 = LDW1(1, 7));
    G1F( 6, pA0, pB0, pA0 = LDW1(0, 8);  pB0 = LDW1(1, 8));
    G1F( 7, pA1, pB1, pA1 = LDW1(0, 9);  pB1 = LDW1(1, 9));
    G1F( 8, pA0, pB0, pA0 = LDW1(0,10);  pB0 = LDW1(1,10));
    G1F( 9, pA1, pB1, pA1 = LDW1(0,11);  pB1 = LDW1(1,11));
    G1F(10, pA0, pB0, pA0 = LDW1(0,12);  pB0 = LDW1(1,12));
    G1F(11, pA1, pB1, pA1 = LDW1(0,13);  pB1 = LDW1(1,13));
    G1F(12, pA0, pB0, pA0 = LDW1(0,14);  pB0 = LDW1(1,14));
    G1F(13, pA1, pB1, pA1 = LDW1(0,15);  pB1 = LDW1(1,15));
    G1F(14, pA0, pB0, );
    G1F(15, pA1, pB1, );
    // p-slots now dead.

    // q bank0: issued here, flies under BOTH GELU stores (p regs recycled)
    q00 = LDW2(0,0); q01 = LDW2(1,0); q02 = LDW2(2,0); q03 = LDW2(3,0);

    // ---- GELU, scale by -dt, write h (bf16) into hs ----
    GELU_STORE(0);
    GELU_STORE(1);

    // q bank1: flies under h-store drain + barrier + first G2K slice
    q10 = LDW2(0,1); q11 = LDW2(1,1); q12 = LDW2(2,1); q13 = LDW2(3,1);
    BAR();

    // ---- GEMM2: z += W2^T * h^T  (K=256), two rolling 4-wide banks ----
    G2K(0, q00, q01, q02, q03, q00=LDW2(0,2); q01=LDW2(1,2); q02=LDW2(2,2); q03=LDW2(3,2));
    G2K(1, q10, q11, q12, q13, q10=LDW2(0,3); q11=LDW2(1,3); q12=LDW2(2,3); q13=LDW2(3,3));
    G2K(2, q00, q01, q02, q03, q00=LDW2(0,4); q01=LDW2(1,4); q02=LDW2(2,4); q03=LDW2(3,4));
    G2K(3, q10, q11, q12, q13, q10=LDW2(0,5); q11=LDW2(1,5); q12=LDW2(2,5); q13=LDW2(3,5));
    G2K(4, q00, q01, q02, q03, q00=LDW2(0,6); q01=LDW2(1,6); q02=LDW2(2,6); q03=LDW2(3,6));
    G2K(5, q10, q11, q12, q13, q10=LDW2(0,7); q11=LDW2(1,7); q12=LDW2(2,7); q13=LDW2(3,7));
    G2K(6, q00, q01, q02, q03, );
    G2K(7, q10, q11, q12, q13, );

    // ---- -dt*b2 bias ----
    #pragma unroll
    for (int nt = 0; nt < 4; ++nt){
      f32x4 b2q = *(const f32x4*)&cst[512 + 64 * w + 16 * nt + 4 * g];
      #pragma unroll
      for (int mt = 0; mt < 4; ++mt)
        #pragma unroll
        for (int r = 0; r < 4; ++r)
          zacc[nt][mt][r] += b2q[r];
    }
  }
#undef G1F
#undef G2K
#undef GELU_STORE

  // ---- write projection (bf16) ----
  #pragma unroll
  for (int nt = 0; nt < 4; ++nt)
    #pragma unroll
    for (int mt = 0; mt < 4; ++mt){
      int mg = m0 + 16 * mt + l4;
      int nq = 64 * w + 16 * nt + 4 * g;
      uint2_ pk;
      pk[0] = cvt_pk_bf16(zacc[nt][mt][0], zacc[nt][mt][1]);
      pk[1] = cvt_pk_bf16(zacc[nt][mt][2], zacc[nt][mt][3]);
      *(uint2_*)(proj + (size_t)mg * 512 + nq) = pk;
    }
}

// ---- classifier: logits = gelu([real||fake] @ W1 + b1) @ W2 + b2 -----------
__global__ __launch_bounds__(512, 2) void cls_kernel(
    const short* __restrict__ mw1t,
    const short* __restrict__ proj_all,
    const float* __restrict__ mb1,
    const float* __restrict__ mw2,
    const float* __restrict__ mb2,
    float* __restrict__ out)
{
  __shared__ __align__(16) float sb1[1024];
  __shared__ __align__(16) float sw2[2048];
  __shared__ __align__(16) float sred[2048];

  const int blk = blockIdx.x;
  const int m0  = blk * 32;
  const int tid = threadIdx.x;
  const int w = tid >> 6, l = tid & 63, l4 = l & 15, g = l >> 4;

  #pragma unroll
  for (int j = 0; j < 2; ++j) sb1[tid + 512 * j] = mb1[tid + 512 * j];
  #pragma unroll
  for (int j = 0; j < 4; ++j) sw2[tid + 512 * j] = mw2[tid + 512 * j];
  __syncthreads();

  float lacc[2][2] = {{0.f, 0.f}, {0.f, 0.f}};

  for (int rnd = 0; rnd < 4; ++rnd){
    f32x4 hacc[2][2];
    #pragma unroll
    for (int nt = 0; nt < 2; ++nt)
      #pragma unroll
      for (int mt = 0; mt < 2; ++mt)
        hacc[nt][mt] = (f32x4){0.f, 0.f, 0.f, 0.f};

    #pragma unroll
    for (int ks = 0; ks < 32; ++ks){
      int gnt0 = rnd * 16 + 2 * w;
      short8 a0 = *(const short8*)(mw1t + ((size_t)((gnt0    ) * 32 + ks) * 64 + l) * 8);
      short8 a1 = *(const short8*)(mw1t + ((size_t)((gnt0 + 1) * 32 + ks) * 64 + l) * 8);
      int k = ks * 32 + 8 * g;   // combined-dim index; uniform side per ks
      const short* src = (k < 512) ? (proj_all + k)
                                   : (proj_all + ((size_t)8192 * 512 - 512) + k);
      #pragma unroll
      for (int mt = 0; mt < 2; ++mt){
        int mg = m0 + 16 * mt + l4;
        short8 b = *(const short8*)(src + (size_t)mg * 512);
        hacc[0][mt] = MFMA16(a0, b, hacc[0][mt]);
        hacc[1][mt] = MFMA16(a1, b, hacc[1][mt]);
      }
    }
    #pragma unroll
    for (int nt = 0; nt < 2; ++nt){
      int nq = (rnd * 16 + 2 * w + nt) * 16 + 4 * g;
      f32x4 bb = *(const f32x4*)(sb1 + nq);
      #pragma unroll
      for (int r = 0; r < 4; ++r){
        float w2c0 = sw2[(nq + r) * 2 + 0];
        float w2c1 = sw2[(nq + r) * 2 + 1];
        #pragma unroll
        for (int mt = 0; mt < 2; ++mt){
          float x  = hacc[nt][mt][r] + bb[r];
          float gv = gelu_f(x);
          lacc[mt][0] = __builtin_fmaf(gv, w2c0, lacc[mt][0]);
          lacc[mt][1] = __builtin_fmaf(gv, w2c1, lacc[mt][1]);
        }
      }
    }
  }

  int part = w * 4 + g;  // 0..31
  #pragma unroll
  for (int mt = 0; mt < 2; ++mt)
    #pragma unroll
    for (int c = 0; c < 2; ++c)
      sred[((16 * mt + l4) * 2 + c) * 32 + part] = lacc[mt][c];
  __syncthreads();
  if (tid < 64){
    int m = tid >> 1, c = tid & 1;
    float s = 0.f;
    #pragma unroll
    for (int p2 = 0; p2 < 32; ++p2) s += sred[(m * 2 + c) * 32 + p2];
    out[(size_t)(m0 + m) * 2 + c] = s + mb2[c];
  }
}

// ---- launch -----------------------------------------------------------------
extern "C" void kernel_launch(void* const* d_in, const int* in_sizes, int n_in,
                              void* d_out, int out_size, void* d_ws, size_t ws_size,
                              hipStream_t stream)
{
  const float* z0  = (const float*)d_in[0];
  const float* rW1 = (const float*)d_in[1];
  const float* rb1 = (const float*)d_in[2];
  const float* rW2 = (const float*)d_in[3];
  const float* rb2 = (const float*)d_in[4];
  const float* fW1 = (const float*)d_in[5];
  const float* fb1 = (const float*)d_in[6];
  const float* fW2 = (const float*)d_in[7];
  const float* fb2 = (const float*)d_in[8];
  const float* mW1 = (const float*)d_in[9];
  const float* mb1 = (const float*)d_in[10];
  const float* mW2 = (const float*)d_in[11];
  const float* mb2 = (const float*)d_in[12];
  float* out = (float*)d_out;

  char* ws = (char*)d_ws;
  short* w1t_all = (short*)(ws);                 //   524288 B (2 nets)
  short* w2t_all = (short*)(ws + 524288);        //   524288 B (2 nets)
  short* mw1t    = (short*)(ws + 1048576);       //  2097152 B
  short* proj    = (short*)(ws + 3145728);       // 16777216 B (real||fake, bf16)

  prep_kernel<<<768, 256, 0, stream>>>(rW1, rW2, fW1, fW2, mW1, w1t_all, w2t_all, mw1t);
  ode_kernel<<<256, 512, 0, stream>>>(z0, w1t_all, w2t_all,
                                      rW1, rb1, rb2, fW1, fb1, fb2, proj);
  cls_kernel<<<256, 512, 0, stream>>>(mw1t, proj, mb1, mW2, mb2, out);
}